// Round 11
// baseline (207.426 us; speedup 1.0000x reference)
//
#include <hip/hip_runtime.h>

#define N_ 64
#define C_ 64
#define T_ 256
#define V_ 25
#define R_ 8
#define O_ 64
constexpr int TV = T_ * V_;           // 6400
constexpr float INV_T = 1.0f / (float)T_;
constexpr int TC = 16;                // t's per fused block
constexpr int NPOS = TC * V_;         // 400
constexpr int NT = NPOS / 16;         // 25 MFMA N-tiles
constexpr int DP = 32;                // padded u,v extent of dT in global
constexpr int UPAD = 40;              // u slots per (o,t) row in x3b
constexpr int X3S = 16 * UPAD + 8;    // 648 halfwords per o_local

typedef __attribute__((ext_vector_type(8))) short s8v;   // 8 bf16 = 4 VGPR
typedef __attribute__((ext_vector_type(4))) short s4v;   // 4 bf16
typedef __attribute__((ext_vector_type(4))) float f4v;   // MFMA acc / float4

__device__ __forceinline__ unsigned short f2bf(float f) {   // RNE f32->bf16
    union { float f; unsigned u; } v; v.f = f;
    unsigned r = v.u + 0x7FFFu + ((v.u >> 16) & 1u);
    return (unsigned short)(r >> 16);
}

// -------- k_mean: xm[n][c][v] = mean_t x[n][c][t][v]  (proven ~19us, ~5.5TB/s)
__global__ __launch_bounds__(256) void k_mean(const float* __restrict__ x,
                                              float* __restrict__ xm) {
    __shared__ float part[8 * V_];
    const int bid = blockIdx.x;           // n*C + c
    const int tid = threadIdx.x;
    const float* xp = x + (size_t)bid * TV;
    if (tid < 200) {
        const int vid = tid % V_;
        const int seg = tid / V_;
        float s = 0.f;
        const float* p = xp + seg * 32 * V_ + vid;
        #pragma unroll
        for (int j = 0; j < 32; ++j) s += p[j * V_];
        part[tid] = s;
    }
    __syncthreads();
    if (tid < V_) {
        float s = 0.f;
        #pragma unroll
        for (int k = 0; k < 8; ++k) s += part[k * V_ + tid];
        xm[(size_t)bid * V_ + tid] = s * INV_T;
    }
}

// -------- k_dmat: dT[n][o][v][u] = d(u,v) bf16, zero-padded to 32x32.
__global__ __launch_bounds__(256) void k_dmat(const float* __restrict__ xm,
                                              const float* __restrict__ A,
                                              const float* __restrict__ w1,
                                              const float* __restrict__ b1,
                                              const float* __restrict__ w2,
                                              const float* __restrict__ b2,
                                              const float* __restrict__ w4,
                                              const float* __restrict__ b4,
                                              unsigned short* __restrict__ dT) {
    __shared__ float xms[C_][V_];
    __shared__ float x1s[R_][V_];
    __shared__ float x2s[R_][V_];
    const int n  = blockIdx.x;
    const int og = blockIdx.y * 8;
    const int tid = threadIdx.x;

    for (int i = tid; i < C_ * V_; i += 256)
        xms[i / V_][i % V_] = xm[(size_t)n * C_ * V_ + i];
    __syncthreads();

    for (int i = tid; i < 2 * R_ * V_; i += 256) {
        const int j = i % (R_ * V_);
        const int r = j / V_, v = j % V_;
        const bool first = (i < R_ * V_);
        const float* w = first ? w1 : w2;
        float acc = first ? b1[r] : b2[r];
        #pragma unroll
        for (int c = 0; c < C_; ++c) acc += w[r * C_ + c] * xms[c][v];
        if (first) x1s[r][v] = acc;
        else       x2s[r][v] = acc;
    }
    __syncthreads();

    unsigned short* dn = dT + (size_t)n * O_ * DP * DP;
    for (int p = tid; p < DP * DP; p += 256) {       // p = v*32+u, coalesced in u
        const int v = p >> 5, u = p & 31;
        if (u < V_ && v < V_) {
            float adjr[R_];
            #pragma unroll
            for (int r = 0; r < R_; ++r) adjr[r] = tanhf(x1s[r][u] - x2s[r][v]);
            const float a = A[u * V_ + v];
            #pragma unroll
            for (int oo = 0; oo < 8; ++oo) {
                const int o = og + oo;
                float acc = b4[o];
                #pragma unroll
                for (int r = 0; r < R_; ++r) acc = fmaf(w4[o * R_ + r], adjr[r], acc);
                dn[(size_t)o * DP * DP + p] = f2bf(acc + a);   // ALPHA == 1
            }
        } else {
            #pragma unroll
            for (int oo = 0; oo < 8; ++oo)
                dn[(size_t)(og + oo) * DP * DP + p] = 0;
        }
    }
}

// -------- k_F v4: GEMM1 (B-frags gathered from global, r5-proven) per o-quarter
//          -> tiny x3b LDS -> GEMM2 with dT prefetched before GEMM1.
//          LDS = 20.7 KB only; __launch_bounds__(512,6) -> >=3 blocks/CU
//          (24+ waves/CU vs r10's 16) so other blocks' memory phases fill
//          this block's barrier/compute bubbles.
__global__ __launch_bounds__(512, 6) void k_F(const float* __restrict__ x,
                                              const float* __restrict__ w3,
                                              const float* __restrict__ b3,
                                              const unsigned short* __restrict__ dT,
                                              float* __restrict__ out) {
    __shared__ __align__(16) unsigned short x3b[16 * X3S];        // 20736 B

    const int n    = blockIdx.y;
    const int tc   = blockIdx.x;
    const int tid  = threadIdx.x;
    const int lane = tid & 63;
    const int wave = tid >> 6;      // 0..7
    const int l16  = lane & 15;
    const int lg   = lane >> 4;     // 0..3

    // zero x3b u-pad [24,32): GEMM1 rewrites u=24 each quarter; [25,32) stays 0
    if (tid < 256) {
        const int o_l = tid >> 4, t = tid & 15;
        *(s8v*)&x3b[o_l * X3S + t * UPAD + 24] = (s8v)0;   // 16B-aligned
    }

    const float* xbase = x + (size_t)n * C_ * TV + tc * NPOS;
    const unsigned short* dn = dT + (size_t)n * O_ * DP * DP;
    float* on = out + (size_t)n * O_ * TV + tc * NPOS;

    #pragma unroll 1
    for (int h = 0; h < 4; ++h) {               // o-quarter: o = h*16 .. h*16+15
        // ---- prefetch this quarter's dT B-frags (latency hides under GEMM1)
        const int o_l0 = wave * 2, o_g0 = h * 16 + o_l0;
        const unsigned short* dp0 = dn + (size_t)o_g0 * DP * DP;
        const s8v pv00 = *(const s8v*)(dp0 + l16 * DP + lg * 8);
        const s8v pv01 = *(const s8v*)(dp0 + (16 + l16) * DP + lg * 8);
        const s8v pv10 = *(const s8v*)(dp0 + DP * DP + l16 * DP + lg * 8);
        const s8v pv11 = *(const s8v*)(dp0 + DP * DP + (16 + l16) * DP + lg * 8);

        // ---- A-frags for this quarter (w3 16KB, L1/L2-resident)
        s8v afr[2];
        #pragma unroll
        for (int kh = 0; kh < 2; ++kh) {
            const float* wp = w3 + (h * 16 + l16) * C_ + kh * 32 + lg * 8;
            s8v f;
            #pragma unroll
            for (int j = 0; j < 8; ++j) f[j] = (short)f2bf(wp[j]);
            afr[kh] = f;
        }
        const f4v b3h = *(const f4v*)(b3 + h * 16 + lg * 4);

        // ---- GEMM1 quarter: B-frags straight from global (L2-warm after h=0)
        #pragma unroll
        for (int i = 0; i < 4; ++i) {
            const int nt = wave + 8 * i;
            if (nt < NT) {
                const int pos = nt * 16 + l16;
                const int t = pos / 25, u = pos - 25 * t;
                s8v bfr[2];
                #pragma unroll
                for (int kh = 0; kh < 2; ++kh) {
                    s8v f;
                    #pragma unroll
                    for (int j = 0; j < 8; ++j)
                        f[j] = (short)f2bf(xbase[(size_t)(kh * 32 + lg * 8 + j) * TV + pos]);
                    bfr[kh] = f;
                }
                f4v acc = (f4v)0.f;
                acc = __builtin_amdgcn_mfma_f32_16x16x32_bf16(afr[0], bfr[0], acc, 0, 0, 0);
                acc = __builtin_amdgcn_mfma_f32_16x16x32_bf16(afr[1], bfr[1], acc, 0, 0, 0);
                // C: col=l16=pos, row=lg*4+r=o-in-tile (verified layout)
                #pragma unroll
                for (int r = 0; r < 4; ++r)
                    x3b[(lg * 4 + r) * X3S + t * UPAD + u] = f2bf(acc[r] + b3h[r]);
            }
        }
        __syncthreads();   // B1: x3b(quarter h) ready

        // ---- GEMM2 quarter: wave owns o_l = wave*2 + {0,1}, dT already in regs
        #pragma unroll
        for (int oo = 0; oo < 2; ++oo) {
            const int o_l = wave * 2 + oo;
            const int o_g = h * 16 + o_l;
            const s8v av  = *(const s8v*)&x3b[o_l * X3S + l16 * UPAD + lg * 8]; // b128
            const s8v bv0 = oo ? pv10 : pv00;
            const s8v bv1 = oo ? pv11 : pv01;
            f4v c0 = (f4v)0.f, c1 = (f4v)0.f;
            c0 = __builtin_amdgcn_mfma_f32_16x16x32_bf16(av, bv0, c0, 0, 0, 0);
            c1 = __builtin_amdgcn_mfma_f32_16x16x32_bf16(av, bv1, c1, 0, 0, 0);
            float* ob = on + (size_t)o_g * TV;
            #pragma unroll
            for (int r = 0; r < 4; ++r) {
                const int t = lg * 4 + r;                       // C: row=t, col=v
                ob[t * 25 + l16] = c0[r];
                if (l16 < 9) ob[t * 25 + 16 + l16] = c1[r];
            }
        }
        __syncthreads();   // B2: protect x3b before next quarter's GEMM1 writes
    }
}

extern "C" void kernel_launch(void* const* d_in, const int* in_sizes, int n_in,
                              void* d_out, int out_size, void* d_ws, size_t ws_size,
                              hipStream_t stream) {
    const float* x  = (const float*)d_in[0];
    const float* A  = (const float*)d_in[1];
    const float* w1 = (const float*)d_in[2];
    const float* b1 = (const float*)d_in[3];
    const float* w2 = (const float*)d_in[4];
    const float* b2 = (const float*)d_in[5];
    const float* w3 = (const float*)d_in[6];
    const float* b3 = (const float*)d_in[7];
    const float* w4 = (const float*)d_in[8];
    const float* b4 = (const float*)d_in[9];

    float* out = (float*)d_out;
    float* xm  = (float*)d_ws;                                          // 0.41 MB f32
    unsigned short* dTm = (unsigned short*)(xm + (size_t)N_ * C_ * V_); // N*O*32*32 bf16 (8.4 MB)

    k_mean<<<N_ * C_, 256, 0, stream>>>(x, xm);
    k_dmat<<<dim3(N_, 8), 256, 0, stream>>>(xm, A, w1, b1, w2, b2, w4, b4, dTm);
    k_F<<<dim3(T_ / TC, N_), 512, 0, stream>>>(x, w3, b3, dTm, out);
}

// Round 12
// 86.821 us; speedup vs baseline: 2.3891x; 2.3891x over previous
//
#include <hip/hip_runtime.h>

#define N_ 64
#define C_ 64
#define T_ 256
#define V_ 25
#define R_ 8
#define O_ 64
constexpr int TV = T_ * V_;           // 6400
constexpr float INV_T = 1.0f / (float)T_;
constexpr int TC = 16;                // t's per fused block
constexpr int NPOS = TC * V_;         // 400
constexpr int NT = NPOS / 16;         // 25 MFMA N-tiles
constexpr int DP = 32;                // padded u,v extent of dT in global
constexpr int UPAD = 40;              // u slots per (o,t) row in x3b
constexpr int X3S = 16 * UPAD + 8;    // 648 halfwords per o_local

typedef __attribute__((ext_vector_type(8))) short s8v;   // 8 bf16 = 4 VGPR
typedef __attribute__((ext_vector_type(4))) short s4v;   // 4 bf16
typedef __attribute__((ext_vector_type(4))) float f4v;   // MFMA acc / float4

__device__ __forceinline__ unsigned short f2bf(float f) {   // RNE f32->bf16
    union { float f; unsigned u; } v; v.f = f;
    unsigned r = v.u + 0x7FFFu + ((v.u >> 16) & 1u);
    return (unsigned short)(r >> 16);
}

// -------- k_mean: xm[n][c][v] = mean_t x[n][c][t][v]  (proven ~19us, ~5.5TB/s)
__global__ __launch_bounds__(256) void k_mean(const float* __restrict__ x,
                                              float* __restrict__ xm) {
    __shared__ float part[8 * V_];
    const int bid = blockIdx.x;           // n*C + c
    const int tid = threadIdx.x;
    const float* xp = x + (size_t)bid * TV;
    if (tid < 200) {
        const int vid = tid % V_;
        const int seg = tid / V_;
        float s = 0.f;
        const float* p = xp + seg * 32 * V_ + vid;
        #pragma unroll
        for (int j = 0; j < 32; ++j) s += p[j * V_];
        part[tid] = s;
    }
    __syncthreads();
    if (tid < V_) {
        float s = 0.f;
        #pragma unroll
        for (int k = 0; k < 8; ++k) s += part[k * V_ + tid];
        xm[(size_t)bid * V_ + tid] = s * INV_T;
    }
}

// -------- k_dmat: dT[n][o][v][u] = d(u,v) bf16, zero-padded to 32x32.
__global__ __launch_bounds__(256) void k_dmat(const float* __restrict__ xm,
                                              const float* __restrict__ A,
                                              const float* __restrict__ w1,
                                              const float* __restrict__ b1,
                                              const float* __restrict__ w2,
                                              const float* __restrict__ b2,
                                              const float* __restrict__ w4,
                                              const float* __restrict__ b4,
                                              unsigned short* __restrict__ dT) {
    __shared__ float xms[C_][V_];
    __shared__ float x1s[R_][V_];
    __shared__ float x2s[R_][V_];
    const int n  = blockIdx.x;
    const int og = blockIdx.y * 8;
    const int tid = threadIdx.x;

    for (int i = tid; i < C_ * V_; i += 256)
        xms[i / V_][i % V_] = xm[(size_t)n * C_ * V_ + i];
    __syncthreads();

    for (int i = tid; i < 2 * R_ * V_; i += 256) {
        const int j = i % (R_ * V_);
        const int r = j / V_, v = j % V_;
        const bool first = (i < R_ * V_);
        const float* w = first ? w1 : w2;
        float acc = first ? b1[r] : b2[r];
        #pragma unroll
        for (int c = 0; c < C_; ++c) acc += w[r * C_ + c] * xms[c][v];
        if (first) x1s[r][v] = acc;
        else       x2s[r][v] = acc;
    }
    __syncthreads();

    unsigned short* dn = dT + (size_t)n * O_ * DP * DP;
    for (int p = tid; p < DP * DP; p += 256) {       // p = v*32+u, coalesced in u
        const int v = p >> 5, u = p & 31;
        if (u < V_ && v < V_) {
            float adjr[R_];
            #pragma unroll
            for (int r = 0; r < R_; ++r) adjr[r] = tanhf(x1s[r][u] - x2s[r][v]);
            const float a = A[u * V_ + v];
            #pragma unroll
            for (int oo = 0; oo < 8; ++oo) {
                const int o = og + oo;
                float acc = b4[o];
                #pragma unroll
                for (int r = 0; r < R_; ++r) acc = fmaf(w4[o * R_ + r], adjr[r], acc);
                dn[(size_t)o * DP * DP + p] = f2bf(acc + a);   // ALPHA == 1
            }
        } else {
            #pragma unroll
            for (int oo = 0; oo < 8; ++oo)
                dn[(size_t)(og + oo) * DP * DP + p] = 0;
        }
    }
}

// -------- k_F v5: r9/r10 schedule, xs eliminated. B-frags hoisted ONCE via
//          direct global gather (r5-proven, 52 VGPR). LDS = x3b only (20.7KB)
//          -> 3-4 blocks/CU (24-32 waves) vs r10's 2. No forced min-waves
//          (r11 lesson: spills). Barrier after pad-zero replaces the old
//          stage-barrier ordering.
__global__ __launch_bounds__(512) void k_F(const float* __restrict__ x,
                                           const float* __restrict__ w3,
                                           const float* __restrict__ b3,
                                           const unsigned short* __restrict__ dT,
                                           float* __restrict__ out) {
    __shared__ __align__(16) unsigned short x3b[16 * X3S];        // 20736 B

    const int n    = blockIdx.y;
    const int tc   = blockIdx.x;
    const int tid  = threadIdx.x;
    const int lane = tid & 63;
    const int wave = tid >> 6;      // 0..7
    const int l16  = lane & 15;
    const int lg   = lane >> 4;     // 0..3

    // zero x3b u-pad [24,32): [25,32) must be 0 for GEMM2's K=32; u=24 is
    // legitimately rewritten by GEMM1 AFTER the barrier below (no race).
    if (tid < 256) {
        const int o_l = tid >> 4, t = tid & 15;
        *(s8v*)&x3b[o_l * X3S + t * UPAD + 24] = (s8v)0;   // 16B-aligned
    }
    __syncthreads();

    // ---- hoist this wave's GEMM1 B-frags: 64 independent dword loads
    const float* xbase = x + (size_t)n * C_ * TV + tc * NPOS;
    s8v bfr[4][2];
    #pragma unroll
    for (int i = 0; i < 4; ++i) {
        const int nt = wave + 8 * i;
        if (nt < NT) {
            const int pos = nt * 16 + l16;
            #pragma unroll
            for (int kh = 0; kh < 2; ++kh) {
                s8v f;
                #pragma unroll
                for (int j = 0; j < 8; ++j)
                    f[j] = (short)f2bf(xbase[(size_t)(kh * 32 + lg * 8 + j) * TV + pos]);
                bfr[i][kh] = f;
            }
        }
    }

    const unsigned short* dn = dT + (size_t)n * O_ * DP * DP;
    float* on = out + (size_t)n * O_ * TV + tc * NPOS;

    #pragma unroll 1
    for (int h = 0; h < 4; ++h) {               // o-quarter: o = h*16 .. h*16+15
        // A-frags for this quarter (w3 16KB, L1/L2-resident)
        s8v afr[2];
        #pragma unroll
        for (int kh = 0; kh < 2; ++kh) {
            const float* wp = w3 + (h * 16 + l16) * C_ + kh * 32 + lg * 8;
            s8v f;
            #pragma unroll
            for (int j = 0; j < 8; ++j) f[j] = (short)f2bf(wp[j]);
            afr[kh] = f;
        }
        const f4v b3h = *(const f4v*)(b3 + h * 16 + lg * 4);

        // GEMM1 quarter: x3[o_l][t][u], o_l = lg*4+r
        #pragma unroll
        for (int i = 0; i < 4; ++i) {
            const int nt = wave + 8 * i;
            if (nt < NT) {
                const int pos = nt * 16 + l16;
                const int t = pos / 25, u = pos - 25 * t;
                f4v acc = (f4v)0.f;
                acc = __builtin_amdgcn_mfma_f32_16x16x32_bf16(afr[0], bfr[i][0], acc, 0, 0, 0);
                acc = __builtin_amdgcn_mfma_f32_16x16x32_bf16(afr[1], bfr[i][1], acc, 0, 0, 0);
                // C: col=l16=pos, row=lg*4+r=o-in-tile (verified layout)
                #pragma unroll
                for (int r = 0; r < 4; ++r)
                    x3b[(lg * 4 + r) * X3S + t * UPAD + u] = f2bf(acc[r] + b3h[r]);
            }
        }
        __syncthreads();   // B1: x3b(quarter h) ready

        // GEMM2 quarter: wave owns o_l = wave*2 + {0,1}; dT b128 from L2
        #pragma unroll
        for (int oo = 0; oo < 2; ++oo) {
            const int o_l = wave * 2 + oo;
            const int o_g = h * 16 + o_l;
            const unsigned short* dp = dn + (size_t)o_g * DP * DP;
            const s8v bv0 = *(const s8v*)(dp + l16 * DP + lg * 8);
            const s8v bv1 = *(const s8v*)(dp + (16 + l16) * DP + lg * 8);
            const s8v av  = *(const s8v*)&x3b[o_l * X3S + l16 * UPAD + lg * 8]; // b128
            f4v c0 = (f4v)0.f, c1 = (f4v)0.f;
            c0 = __builtin_amdgcn_mfma_f32_16x16x32_bf16(av, bv0, c0, 0, 0, 0);
            c1 = __builtin_amdgcn_mfma_f32_16x16x32_bf16(av, bv1, c1, 0, 0, 0);
            float* ob = on + (size_t)o_g * TV;
            #pragma unroll
            for (int r = 0; r < 4; ++r) {
                const int t = lg * 4 + r;                       // C: row=t, col=v
                ob[t * 25 + l16] = c0[r];
                if (l16 < 9) ob[t * 25 + 16 + l16] = c1[r];
            }
        }
        __syncthreads();   // B2: protect x3b before next quarter's GEMM1 writes
    }
}

extern "C" void kernel_launch(void* const* d_in, const int* in_sizes, int n_in,
                              void* d_out, int out_size, void* d_ws, size_t ws_size,
                              hipStream_t stream) {
    const float* x  = (const float*)d_in[0];
    const float* A  = (const float*)d_in[1];
    const float* w1 = (const float*)d_in[2];
    const float* b1 = (const float*)d_in[3];
    const float* w2 = (const float*)d_in[4];
    const float* b2 = (const float*)d_in[5];
    const float* w3 = (const float*)d_in[6];
    const float* b3 = (const float*)d_in[7];
    const float* w4 = (const float*)d_in[8];
    const float* b4 = (const float*)d_in[9];

    float* out = (float*)d_out;
    float* xm  = (float*)d_ws;                                          // 0.41 MB f32
    unsigned short* dTm = (unsigned short*)(xm + (size_t)N_ * C_ * V_); // N*O*32*32 bf16 (8.4 MB)

    k_mean<<<N_ * C_, 256, 0, stream>>>(x, xm);
    k_dmat<<<dim3(N_, 8), 256, 0, stream>>>(xm, A, w1, b1, w2, b2, w4, b4, dTm);
    k_F<<<dim3(T_ / TC, N_), 512, 0, stream>>>(x, w3, b3, dTm, out);
}